// Round 8
// baseline (252.542 us; speedup 1.0000x reference)
//
#include <hip/hip_runtime.h>
#include <hip/hip_bf16.h>

// Temporal_Aggregation — LDS-free streaming MFMA kernel (MI355X gfx950).
//
// Folded math (validated rounds 4-7):
//   Wbig[o][j=k*64+i] = sum_c Wlin[o][c]*Wconv[c][i][0][k]   (bf16 in ws)
//   z[t][o]  = sum_j Vp[t+(j>>6)][j&63] * Wbig[o][j]
//   out[t][o] = relu( z[t-1]+z[t]+z[t+1] (clipped) + m_t*biasC[o] + blin[o] )
//
// Round-8 structure (fixing round-7 latency-boundness):
//  - Operand swap: A = W, B = V  =>  D col = lane15 = t, row = o.
//    The V B-fragment (lane15 = t-row, 8 contiguous k = 8 contiguous channels
//    at one conv tap) is 32 contiguous fp32 bytes in GLOBAL memory — so no
//    LDS, no barriers, no staging. fp32->bf16 conversion in registers.
//  - One wave = one (b,n) row: 2 N-tiles (t=0..23 + 8 dead lanes), 4 o-tiles.
//    acc[2][4] = 32 VGPRs. T-edge conv taps: clamp address + zero-select.
//  - Band-sum along lane15 via ds_bpermute rotations; the cross-N-tile
//    boundary value comes from a register select (lane15==15/0 trick); all
//    invalid neighbors coincide exactly with t==0 / t==23 masking.

typedef __attribute__((ext_vector_type(8))) short short8;
typedef __attribute__((ext_vector_type(8))) __bf16 bf16x8;
typedef __attribute__((ext_vector_type(4))) float f4;

// ---- Kernel 1: fold conv+linear weights -------------------------------------
// ws bytes: [0,24576) Wbig bf16[64][192]; [24576,24832) biasC f32[64];
//           [24832,25088) blinF f32[64]
__global__ void prep_kernel(const float* __restrict__ Wconv,
                            const float* __restrict__ bconv,
                            const float* __restrict__ Wlin,
                            const float* __restrict__ blin,
                            __hip_bfloat16* __restrict__ wbig,
                            float* __restrict__ biasC,
                            float* __restrict__ blinF) {
    __shared__ float Wl[4096];
    const int tid = threadIdx.x;
    for (int c = tid; c < 4096; c += 256) Wl[c] = Wlin[c];
    __syncthreads();
    int idx = blockIdx.x * 256 + tid;
    if (idx < 64 * 192) {
        int o = idx / 192;
        int j = idx - o * 192;
        int k = j >> 6;
        int i = j & 63;
        float acc = 0.0f;
        for (int c = 0; c < 64; ++c)
            acc += Wl[o * 64 + c] * Wconv[c * 192 + i * 3 + k];
        wbig[o * 192 + j] = __float2bfloat16(acc);
    } else if (idx < 64 * 192 + 64) {
        int o = idx - 64 * 192;
        float acc = 0.0f;
        for (int c = 0; c < 64; ++c)
            acc += Wl[o * 64 + c] * bconv[c];
        biasC[o] = acc;
    } else if (idx < 64 * 192 + 128) {
        int o = idx - (64 * 192 + 64);
        blinF[o] = blin[o];
    }
}

__device__ __forceinline__ float bperm(int idx, float v) {
    return __int_as_float(__builtin_amdgcn_ds_bpermute(idx, __float_as_int(v)));
}

// ---- Kernel 2: streaming conv-GEMM + band sum + bias + relu -----------------
__global__ __launch_bounds__(256, 4) void fused_kernel(
    const float* __restrict__ value,
    const __hip_bfloat16* __restrict__ wbig,
    const float* __restrict__ biasC,
    const float* __restrict__ blinF,
    float* __restrict__ out) {
    const int tid = threadIdx.x;
    const int lane = tid & 63;
    const int lane15 = lane & 15;
    const int quad = lane >> 4;
    const long row = (long)blockIdx.x * 4 + (tid >> 6);   // one (b,n) row per wave
    const float* vrow = value + row * 1536;

    f4 acc[2][4];
    #pragma unroll
    for (int nt = 0; nt < 2; ++nt)
        #pragma unroll
        for (int mt = 0; mt < 4; ++mt) {
            f4 zz = {0.f, 0.f, 0.f, 0.f};
            acc[nt][mt] = zz;
        }

    const short* wsrc = (const short*)wbig;
    const int wko = lane15 * 192 + quad * 8;   // W frag: lane15 = o_local
    const short8 z8 = {0, 0, 0, 0, 0, 0, 0, 0};

    #pragma unroll
    for (int ks = 0; ks < 6; ++ks) {
        // W (A-operand) fragments, straight from global (L1-hot, 24.6 KB)
        bf16x8 wf[4];
        #pragma unroll
        for (int mt = 0; mt < 4; ++mt)
            wf[mt] = __builtin_bit_cast(bf16x8,
                *(const short8*)(wsrc + mt * 16 * 192 + wko + ks * 32));
        const int tau = ks >> 1;               // conv tap
        const int i0 = (ks & 1) * 32 + quad * 8;
        #pragma unroll
        for (int nt = 0; nt < 2; ++nt) {
            // V (B-operand) fragment: lane15 = t-row, 8 contiguous channels
            int m = nt * 16 + lane15;
            int st = m + tau - 1;
            bool valid = (st >= 0) && (st < 24);
            int stc = st < 0 ? 0 : (st > 23 ? 23 : st);
            const float* src = vrow + stc * 64 + i0;
            f4 lo = *(const f4*)(src);
            f4 hi = *(const f4*)(src + 4);
            short8 vs;
            vs[0] = (short)__bfloat16_as_ushort(__float2bfloat16(lo.x));
            vs[1] = (short)__bfloat16_as_ushort(__float2bfloat16(lo.y));
            vs[2] = (short)__bfloat16_as_ushort(__float2bfloat16(lo.z));
            vs[3] = (short)__bfloat16_as_ushort(__float2bfloat16(lo.w));
            vs[4] = (short)__bfloat16_as_ushort(__float2bfloat16(hi.x));
            vs[5] = (short)__bfloat16_as_ushort(__float2bfloat16(hi.y));
            vs[6] = (short)__bfloat16_as_ushort(__float2bfloat16(hi.z));
            vs[7] = (short)__bfloat16_as_ushort(__float2bfloat16(hi.w));
            vs = valid ? vs : z8;
            bf16x8 vfrag = __builtin_bit_cast(bf16x8, vs);
            #pragma unroll
            for (int mt = 0; mt < 4; ++mt)
                acc[nt][mt] = __builtin_amdgcn_mfma_f32_16x16x32_bf16(
                    wf[mt], vfrag, acc[nt][mt], 0, 0, 0);
        }
    }

    // ---- epilogue: band sum along lane15 (bpermute), bias, relu, store ----
    // D layout: col = lane15 = t (within nt tile), row = o_local = quad*4+i.
    const int idxP = ((quad << 4) | ((lane15 + 15) & 15)) << 2;
    const int idxN = ((quad << 4) | ((lane15 + 1) & 15)) << 2;
    const bool sel15 = (lane15 == 15);
    const bool sel0 = (lane15 == 0);
    const bool valid_m1 = (lane15 < 8);        // nt=1 live lanes (m = 16+l < 24)

    #pragma unroll
    for (int mt = 0; mt < 4; ++mt) {
        // per-(mt) bias vectors for this lane's 4 o values (o = mt*16+quad*4+i)
        f4 bc = *(const f4*)(biasC + mt * 16 + quad * 4);
        f4 bl = *(const f4*)(blinF + mt * 16 + quad * 4);
        #pragma unroll
        for (int nt = 0; nt < 2; ++nt) {
            const int m = nt * 16 + lane15;
            const bool has_prev = (nt == 1) || (lane15 != 0);
            const bool has_next = (nt == 0) || (lane15 != 7);
            const bool edge = (nt == 0) ? sel0 : (lane15 == 7);
            const bool do_store = (nt == 0) || valid_m1;
            long obase = row * 1536 + m * 64 + mt * 16 + quad * 4;
            #pragma unroll
            for (int i = 0; i < 4; ++i) {
                float zc = acc[nt][mt][i];
                // prev source register: lane15==15 lanes supply acc[nt-1]
                float xp = (nt == 1 && sel15) ? acc[0][mt][i] : acc[nt][mt][i];
                // next source register: lane15==0 lanes supply acc[nt+1]
                float xn = (nt == 0 && sel0) ? acc[1][mt][i] : acc[nt][mt][i];
                float prev = bperm(idxP, xp);
                float next = bperm(idxN, xn);
                float s = zc;
                if (has_prev) s += prev;
                if (has_next) s += next;
                float bias = (edge ? 2.0f : 3.0f) * bc[i] + bl[i];
                float r = fmaxf(s + bias, 0.0f);
                if (do_store) out[obase + i] = r;
            }
        }
    }
}

extern "C" void kernel_launch(void* const* d_in, const int* in_sizes, int n_in,
                              void* d_out, int out_size, void* d_ws, size_t ws_size,
                              hipStream_t stream) {
    const float* value = (const float*)d_in[0];
    const float* Wconv = (const float*)d_in[1];
    const float* bconv = (const float*)d_in[2];
    const float* Wlin  = (const float*)d_in[3];
    const float* blin  = (const float*)d_in[4];
    float* out = (float*)d_out;

    __hip_bfloat16* wbig = (__hip_bfloat16*)d_ws;
    float* biasC = (float*)((char*)d_ws + 24576);
    float* blinF = (float*)((char*)d_ws + 24832);

    prep_kernel<<<49, 256, 0, stream>>>(Wconv, bconv, Wlin, blin, wbig, biasC, blinF);
    // 16384 rows, 1 row per wave, 4 waves per block -> 4096 blocks
    fused_kernel<<<4096, 256, 0, stream>>>(value, wbig, biasC, blinF, out);
}

// Round 9
// 193.618 us; speedup vs baseline: 1.3043x; 1.3043x over previous
//
#include <hip/hip_runtime.h>
#include <hip/hip_bf16.h>

// Temporal_Aggregation — MFMA bf16, fp32 I/O (MI355X gfx950). Round 9.
//
// Folded math (validated rounds 4-8):
//   Wbig[o][j=k*64+i] = sum_c Wlin[o][c]*Wconv[c][i][0][k]   (bf16 in ws)
//   z[t][o]  = sum_j Vp[t+(j>>6)][j&63] * Wbig[o][j]
//   out[t][o] = relu( z[t-1]+z[t]+z[t+1] (clipped) + m_t*biasC[o] + blin[o] )
//
// Round-9 = round-6 block shape x round-7 wave mapping:
//  - 2048 independent blocks, 8 rows each, single 29952 B LDS V-buffer,
//    ONE barrier. 4-5 blocks/CU co-resident -> cross-block TLP hides staging
//    latency (round-7's persistent 2-block version couldn't; round-8's
//    in-loop global loads serialized on vmcnt with only 52 VGPRs).
//  - N-split waves: wave owns one 16-col N-tile; its 6 B-fragments live in
//    24 VGPRs loaded from global BEFORE staging -> K-loop is pure
//    ds_read_b128 + MFMA (no vmcnt inside).
//  - Wave-local register band-sum epilogue (round-7 shuffle scheme).

typedef __attribute__((ext_vector_type(8))) short short8;
typedef __attribute__((ext_vector_type(8))) __bf16 bf16x8;
typedef __attribute__((ext_vector_type(4))) float f4;

#define R_ROWS 8                 // rows per block
#define VP_STRIDE 72             // 64 + 8 pad shorts
#define V_ROW_ELEMS (26 * VP_STRIDE)   // 1872 shorts (pad + 24 + pad)

__device__ __forceinline__ unsigned short f2bfu(float f) {
    return __bfloat16_as_ushort(__float2bfloat16(f));
}

// ---- Kernel 1: fold conv+linear weights -------------------------------------
// ws bytes: [0,24576) Wbig bf16[64][192]; [24576,24832) biasC f32[64];
//           [24832,25088) blinF f32[64]
__global__ void prep_kernel(const float* __restrict__ Wconv,
                            const float* __restrict__ bconv,
                            const float* __restrict__ Wlin,
                            const float* __restrict__ blin,
                            __hip_bfloat16* __restrict__ wbig,
                            float* __restrict__ biasC,
                            float* __restrict__ blinF) {
    __shared__ float Wl[4096];
    const int tid = threadIdx.x;
    for (int c = tid; c < 4096; c += 256) Wl[c] = Wlin[c];
    __syncthreads();
    int idx = blockIdx.x * 256 + tid;
    if (idx < 64 * 192) {
        int o = idx / 192;
        int j = idx - o * 192;
        int k = j >> 6;
        int i = j & 63;
        float acc = 0.0f;
        for (int c = 0; c < 64; ++c)
            acc += Wl[o * 64 + c] * Wconv[c * 192 + i * 3 + k];
        wbig[o * 192 + j] = __float2bfloat16(acc);
    } else if (idx < 64 * 192 + 64) {
        int o = idx - 64 * 192;
        float acc = 0.0f;
        for (int c = 0; c < 64; ++c)
            acc += Wl[o * 64 + c] * bconv[c];
        biasC[o] = acc;
    } else if (idx < 64 * 192 + 128) {
        int o = idx - (64 * 192 + 64);
        blinF[o] = blin[o];
    }
}

// ---- Kernel 2: fused conv-GEMM + band sum + bias + relu ---------------------
__global__ __launch_bounds__(256, 4) void fused_kernel(
    const float* __restrict__ value,
    const __hip_bfloat16* __restrict__ wbig,
    const float* __restrict__ biasC,
    const float* __restrict__ blinF,
    float* __restrict__ out) {
    __shared__ __align__(16) short Vlds[R_ROWS * V_ROW_ELEMS];   // 29952 B

    const int tid = threadIdx.x;
    const int wave = tid >> 6;            // = N-tile index (16 o-columns)
    const int lane = tid & 63;
    const int lane15 = lane & 15;
    const int quad = lane >> 4;
    const long base_row = (long)blockIdx.x * R_ROWS;

    // ---- B fragments for this wave's N-tile (issued first, in flight) ----
    const short* wsrc = (const short*)wbig;
    const int k0 = quad * 8;
    bf16x8 breg[6];
    #pragma unroll
    for (int ks = 0; ks < 6; ++ks)
        breg[ks] = __builtin_bit_cast(bf16x8,
            *(const short8*)(wsrc + (wave * 16 + lane15) * 192 + ks * 32 + k0));

    // ---- stage value: 8 rows x 24x64 fp32 -> bf16 padded LDS ----
    f4 pre[12];
    int loff[12];
    {
        const float* vb = value + base_row * 1536;
        #pragma unroll
        for (int j = 0; j < 12; ++j) {
            int c4 = tid + 256 * j;       // 0..3071
            int r = c4 / 384;
            int rem = c4 - r * 384;
            int t = rem >> 4;
            int d4 = (rem & 15) << 2;
            pre[j] = *(const f4*)(vb + r * 1536 + t * 64 + d4);
            loff[j] = r * V_ROW_ELEMS + (t + 1) * VP_STRIDE + d4;
        }
    }
    if (tid < 128) {                       // zero pad rows 0 and 25
        int r = tid >> 4;
        int which = (tid >> 3) & 1;
        int d8 = (tid & 7) << 3;
        uint4 z; z.x = 0; z.y = 0; z.z = 0; z.w = 0;
        *(uint4*)(Vlds + r * V_ROW_ELEMS + which * (25 * VP_STRIDE) + d8) = z;
    }
    #pragma unroll
    for (int j = 0; j < 12; ++j) {
        ushort4 u;
        u.x = f2bfu(pre[j].x); u.y = f2bfu(pre[j].y);
        u.z = f2bfu(pre[j].z); u.w = f2bfu(pre[j].w);
        *(ushort4*)(Vlds + loff[j]) = u;
    }
    __syncthreads();

    // ---- K-loop: 12 M-tiles x this wave's N-tile, K=192, pure LDS+MFMA ----
    int aoff[12];
    #pragma unroll
    for (int mt = 0; mt < 12; ++mt) {
        int m = mt * 16 + lane15;          // GEMM row, m = r*24 + s
        int r = m / 24;
        int s = m - r * 24;
        aoff[mt] = r * V_ROW_ELEMS + s * VP_STRIDE;
    }
    f4 acc[12];
    #pragma unroll
    for (int mt = 0; mt < 12; ++mt) {
        f4 zz = {0.f, 0.f, 0.f, 0.f};
        acc[mt] = zz;
    }
    #pragma unroll
    for (int ks = 0; ks < 6; ++ks) {
        int k = ks * 32 + k0;
        int ka = ((k >> 6) * VP_STRIDE) + (k & 63);
        #pragma unroll
        for (int mt = 0; mt < 12; ++mt) {
            bf16x8 a = __builtin_bit_cast(bf16x8,
                *(const short8*)(Vlds + aoff[mt] + ka));
            acc[mt] = __builtin_amdgcn_mfma_f32_16x16x32_bf16(
                a, breg[ks], acc[mt], 0, 0, 0);
        }
    }

    // ---- epilogue: wave-local band sum (shuffles), bias, relu, store ----
    // C/D layout: col = lane&15, row16 = quad*4 + i  [m89]
    const int o = wave * 16 + lane15;
    const float bc = biasC[o];
    const float bl = blinF[o];
    const float b3 = 3.0f * bc + bl;
    const float b2 = 2.0f * bc + bl;
    const int srcP = (lane + 48) & 63;
    const int srcN = (lane + 16) & 63;
    #pragma unroll
    for (int mt = 0; mt < 12; ++mt) {
        const int mtp = (mt > 0) ? mt - 1 : 0;
        const int mtn = (mt < 11) ? mt + 1 : 11;
        float pin = __shfl(acc[mt][3], srcP, 64);
        float pxr = __shfl(acc[mtp][3], srcP, 64);
        float nin = __shfl(acc[mt][0], srcN, 64);
        float nxr = __shfl(acc[mtn][0], srcN, 64);
        float prev0 = (quad == 0) ? pxr : pin;
        float next3 = (quad == 3) ? nxr : nin;
        #pragma unroll
        for (int i = 0; i < 4; ++i) {
            int rowq = mt * 16 + quad * 4 + i;  // 0..191
            int rr = rowq / 24;
            int t = rowq - rr * 24;
            float s = acc[mt][i];
            float prev = (i > 0) ? acc[mt][i - 1] : prev0;
            float next = (i < 3) ? acc[mt][i + 1] : next3;
            if (t > 0)  s += prev;
            if (t < 23) s += next;
            float r = fmaxf(s + ((t == 0 || t == 23) ? b2 : b3), 0.0f);
            out[((base_row + rr) * 24 + t) * 64 + o] = r;
        }
    }
}

extern "C" void kernel_launch(void* const* d_in, const int* in_sizes, int n_in,
                              void* d_out, int out_size, void* d_ws, size_t ws_size,
                              hipStream_t stream) {
    const float* value = (const float*)d_in[0];
    const float* Wconv = (const float*)d_in[1];
    const float* bconv = (const float*)d_in[2];
    const float* Wlin  = (const float*)d_in[3];
    const float* blin  = (const float*)d_in[4];
    float* out = (float*)d_out;

    __hip_bfloat16* wbig = (__hip_bfloat16*)d_ws;
    float* biasC = (float*)((char*)d_ws + 24576);
    float* blinF = (float*)((char*)d_ws + 24832);

    prep_kernel<<<49, 256, 0, stream>>>(Wconv, bconv, Wlin, blin, wbig, biasC, blinF);
    // 16384 rows / 8 per block = 2048 blocks
    fused_kernel<<<2048, 256, 0, stream>>>(value, wbig, biasC, blinF, out);
}